// Round 3
// baseline (12526.752 us; speedup 1.0000x reference)
//
#include <hip/hip_runtime.h>
#include <hip/hip_cooperative_groups.h>
#include <cmath>

namespace cg = cooperative_groups;

// IDIM=256, CDIM=512, NH=2, N=128, M=64, T=64, BSZ=128
// x = [emb 0..255 | reads0 256..319 | reads1 320..383 | h 384..895], K=896
// gates rows 2048. Persistent cooperative kernel: weights + NTM memory LDS-resident.

// ---- LDS float offsets (dynamic shared) ----
#define OFF_W     0      // gates W tile  [64 rows][32 f4 slots]      = 8192 floats
#define OFF_PW    8192   // proj W tile   [32 rows][16 f4 slots]      = 2048
#define OFF_MEM   10240  // mem[b]        [128][66]                   = 8448
#define OFF_WPREV 18688  // prev weights  [typ 2][hi 2][128]          = 512
#define OFF_PROJ  19200  // proj vector   [544]
#define OFF_WG2   19744  // [2][128]
#define OFF_WF    20000  // [2][128]
#define OFF_RED   20256  // [16]
#define OFF_EA    20272  // [128]
#define OFF_RVP   20400  // [8][66] = 528
#define OFF_X     20944  // x_s [128][32 f4] = 16384 floats (aliased by hx_s [128][16 f4])
#define SMEM_FLOATS 37328
#define SMEM_BYTES  (SMEM_FLOATS * 4)

// ---- ws float offsets ----
#define WS_X    0        // x_full [128][896]      = 114688
#define WS_C    114688   // c      [128][512]      = 65536
#define WS_PART 180224   // partials [8][128][2048] = 2097152 ; part2 [8][128][544] aliases
// total = 2277376 floats (9.1 MB)

__device__ __forceinline__ float sigm(float x) { return 1.0f / (1.0f + expf(-x)); }
__device__ __forceinline__ float softplusf(float x) {
    return fmaxf(x, 0.0f) + log1pf(expf(-fabsf(x)));
}

__global__ void __launch_bounds__(512, 1) k_persist(
    const float* __restrict__ embs, const int* __restrict__ lens,
    const float* __restrict__ mem_bias,
    const float* __restrict__ W_ih, const float* __restrict__ W_hh,
    const float* __restrict__ b_ih, const float* __restrict__ b_hh,
    const float* __restrict__ Wr, const float* __restrict__ br,
    const float* __restrict__ Ww, const float* __restrict__ bw,
    const float* __restrict__ h0, const float* __restrict__ c0,
    const float* __restrict__ r0,
    float* __restrict__ out, float* __restrict__ ws)
{
    extern __shared__ float smem[];
    cg::grid_group grid = cg::this_grid();
    const int bid = blockIdx.x;
    const int tx  = threadIdx.x;

    float* x_full   = ws + WS_X;
    float* c_ws     = ws + WS_C;
    float* partials = ws + WS_PART;
    float* part2    = ws + WS_PART;     // disjoint lifetime alias

    float4* w_s4  = (float4*)(smem + OFF_W);
    float4* pw_s4 = (float4*)(smem + OFF_PW);
    float*  mem_s   = smem + OFF_MEM;
    float*  wprev_s = smem + OFF_WPREV;
    float*  proj_s  = smem + OFF_PROJ;
    float*  wg2_s   = smem + OFF_WG2;
    float*  wf_s    = smem + OFF_WF;
    float*  red_s   = smem + OFF_RED;
    float*  ea_s    = smem + OFF_EA;
    float*  rvp_s   = smem + OFF_RVP;
    float4* x_s4  = (float4*)(smem + OFF_X);
    float4* hx_s4 = (float4*)(smem + OFF_X);

    // gates decomposition: 256 blocks = 32 row-tiles(64) x 8 k-chunks(112)
    const int rt = bid >> 3, kz = bid & 7;
    const int r0g = rt * 64, k0 = kz * 112;
    // wave-tile map: wave covers 8 row-groups x 8 col-groups (conflict-free b128)
    const int lane = tx & 63, wid = tx >> 6;
    const int rgl = lane >> 3, bgl = lane & 7;
    const int rg = (wid & 1) * 8 + rgl;   // 0..15
    const int bg = (wid >> 1) * 8 + bgl;  // 0..31

    // ================= init (once) =================
    // gates weights -> LDS (64 rows x 28 f4), swizzle slot = kq ^ ((row>>2)&7)
#pragma unroll
    for (int it = 0; it < 4; ++it) {
        int f = it * 512 + tx;
        if (f < 1792) {
            unsigned row = (unsigned)f / 28u; int kq = f - row * 28;
            int kg = k0 + kq * 4, r = r0g + (int)row;
            float4 v = (kg < 384) ? *(const float4*)&W_ih[r * 384 + kg]
                                  : *(const float4*)&W_hh[r * 512 + (kg - 384)];
            w_s4[row * 32 + (kq ^ ((row >> 2) & 7))] = v;
        }
    }
    // proj weights -> LDS: blocks 0..135 = 17 j-tiles(32) x 8 k-chunks(64)
    if (bid < 136) {
        int jt = bid / 8, kz2 = bid - jt * 8;
        int jj = tx >> 4, kq = tx & 15;
        int j = jt * 32 + jj;
        float4 v = make_float4(0.f, 0.f, 0.f, 0.f);
        if (j < 536) {
            int hi = j >= 268; int q = j - hi * 268;
            int kg = kz2 * 64 + kq * 4;
            v = (q < 70) ? *(const float4*)&Wr[(hi * 70 + q) * 512 + kg]
                         : *(const float4*)&Ww[(hi * 198 + (q - 70)) * 512 + kg];
        }
        pw_s4[jj * 16 + (kq ^ ((jj >> 1) & 7))] = v;
    }
    // NTM memory + prev-weights resident (blocks 0..127 own batch b = bid)
    if (bid < 128) {
#pragma unroll
        for (int it = 0; it < 16; ++it) {
            int f = it * 512 + tx;
            mem_s[(f >> 6) * 66 + (f & 63)] = mem_bias[f];
        }
        wprev_s[tx] = 0.f;   // 512 floats: [typ][hi][128]
    }
    // global state init
    {
        int gid = bid * 512 + tx;
        if (gid < 65536) {
            c_ws[gid] = c0[gid & 511];
            x_full[(gid >> 9) * 896 + 384 + (gid & 511)] = h0[gid & 511];
        }
        if (gid < 32768) x_full[(gid >> 8) * 896 + (gid & 255)] = embs[gid];  // t=0
        if (gid < 16384) x_full[(gid >> 7) * 896 + 256 + (gid & 127)] = r0[gid & 127];
    }
    grid.sync();

    // ================= time loop =================
    for (int t = 0; t < 64; ++t) {
        // ---- phase 1: gates partial GEMM (all 256 blocks) ----
        {
#pragma unroll
            for (int it = 0; it < 7; ++it) {
                int f = it * 512 + tx;                  // 3584 f4 = [128 col][28 kq]
                unsigned col = (unsigned)f / 28u; int kq = f - col * 28;
                x_s4[col * 32 + (kq ^ ((col >> 2) & 7))] =
                    *(const float4*)&x_full[col * 896 + k0 + kq * 4];
            }
            __syncthreads();
            float acc[4][4] = {};
#pragma unroll 4
            for (int kk4 = 0; kk4 < 28; ++kk4) {
                float4 wv[4], xv[4];
#pragma unroll
                for (int i = 0; i < 4; ++i)
                    wv[i] = w_s4[(rg * 4 + i) * 32 + (kk4 ^ (rg & 7))];
#pragma unroll
                for (int j = 0; j < 4; ++j)
                    xv[j] = x_s4[(bg * 4 + j) * 32 + (kk4 ^ (bg & 7))];
#pragma unroll
                for (int i = 0; i < 4; ++i)
#pragma unroll
                    for (int j = 0; j < 4; ++j)
                        acc[i][j] += wv[i].x * xv[j].x + wv[i].y * xv[j].y
                                   + wv[i].z * xv[j].z + wv[i].w * xv[j].w;
            }
#pragma unroll
            for (int j = 0; j < 4; ++j) {
                int b = bg * 4 + j;
                *(float4*)&partials[(size_t)kz * 262144 + b * 2048 + r0g + rg * 4] =
                    make_float4(acc[0][j], acc[1][j], acc[2][j], acc[3][j]);
            }
        }
        grid.sync();

        // ---- phase 2: LSTM pointwise (blocks 0..127) ----
        if (bid < 128) {
            int cell = bid * 512 + tx;
            int b = cell >> 9, ch = cell & 511;
            float g4[4];
#pragma unroll
            for (int g = 0; g < 4; ++g) {
                int r = g * 512 + ch;
                float s = b_ih[r] + b_hh[r];
#pragma unroll
                for (int kq = 0; kq < 8; ++kq)
                    s += partials[(size_t)kq * 262144 + b * 2048 + r];
                g4[g] = s;
            }
            float c_old = c_ws[cell];
            float c_new = sigm(g4[1]) * c_old + sigm(g4[0]) * tanhf(g4[2]);
            float h_new = sigm(g4[3]) * tanhf(c_new);
            c_ws[cell] = c_new;
            x_full[b * 896 + 384 + ch] = h_new;
            out[((size_t)t * 128 + b) * 640 + ch] = h_new;
            if (lens[b] - 1 == t) {
                out[5242880 + cell] = h_new;
                out[5308416 + cell] = c_new;
            }
        }
        grid.sync();

        // ---- phase 3: proj partial GEMM (blocks 0..135) + embs prefetch (136..255) ----
        if (bid < 136) {
            int jt = bid / 8, kz2 = bid - jt * 8;
            int hk0 = 384 + kz2 * 64;
#pragma unroll
            for (int it = 0; it < 4; ++it) {
                int f = it * 512 + tx;                 // 2048 f4 = [128 col][16 kq]
                int col = f >> 4, kq = f & 15;
                hx_s4[col * 16 + (kq ^ ((col >> 2) & 7))] =
                    *(const float4*)&x_full[col * 896 + hk0 + kq * 4];
            }
            __syncthreads();
            float a2[2][4] = {};
#pragma unroll
            for (int kk4 = 0; kk4 < 16; ++kk4) {
                float4 wv0 = pw_s4[(rg * 2) * 16 + (kk4 ^ (rg & 7))];
                float4 wv1 = pw_s4[(rg * 2 + 1) * 16 + (kk4 ^ (rg & 7))];
                float4 xv[4];
#pragma unroll
                for (int j = 0; j < 4; ++j)
                    xv[j] = hx_s4[(bg * 4 + j) * 16 + (kk4 ^ (bg & 7))];
#pragma unroll
                for (int j = 0; j < 4; ++j) {
                    a2[0][j] += wv0.x * xv[j].x + wv0.y * xv[j].y + wv0.z * xv[j].z + wv0.w * xv[j].w;
                    a2[1][j] += wv1.x * xv[j].x + wv1.y * xv[j].y + wv1.z * xv[j].z + wv1.w * xv[j].w;
                }
            }
#pragma unroll
            for (int i = 0; i < 2; ++i) {
                int j = jt * 32 + rg * 2 + i;
                if (j < 536) {
#pragma unroll
                    for (int q = 0; q < 4; ++q)
                        part2[(size_t)kz2 * 69632 + (bg * 4 + q) * 544 + j] = a2[i][q];
                }
            }
        } else if (t < 63) {
            int id = (bid - 136) * 512 + tx;
            if (id < 8192) {
                int b = id >> 6, kq = id & 63;
                *(float4*)&x_full[b * 896 + kq * 4] =
                    *(const float4*)&embs[(size_t)(t + 1) * 32768 + b * 256 + kq * 4];
            }
        }
        grid.sync();

        // ---- phase 4: NTM memory ops (blocks 0..127, b = bid) ----
        if (bid < 128) {
            const int b = bid;
            for (int j = tx; j < 536; j += 512) {
                int hi = j >= 268; int q = j - hi * 268;
                float s = (q < 70) ? br[hi * 70 + q] : bw[hi * 198 + (q - 70)];
#pragma unroll
                for (int kq = 0; kq < 8; ++kq)
                    s += part2[(size_t)kq * 69632 + b * 544 + j];
                proj_s[j] = s;
            }
            __syncthreads();
            const int lx = tx & 127;
            const int grp = tx >> 7;      // 0..3; grps 2,3 duplicate 0,1 (same bits)
            const int typ = grp & 1;      // 0 = read head, 1 = write head
            for (int hi = 0; hi < 2; ++hi) {
                const float* p = proj_s + hi * 268 + typ * 70;
                float* wprev = wprev_s + typ * 256 + hi * 128;
                float beta = softplusf(p[64]);
                float g = sigm(p[65]);
                float s0 = p[66], s1 = p[67], s2 = p[68];
                float smx = fmaxf(s0, fmaxf(s1, s2));
                float e0 = expf(s0 - smx), e1 = expf(s1 - smx), e2 = expf(s2 - smx);
                float sden = e0 + e1 + e2;
                s0 = e0 / sden; s1 = e1 / sden; s2 = e2 / sden;
                float gamma = 1.0f + softplusf(p[69]);
                const float* mrow = mem_s + lx * 66;
                float dot = 0.f, nm = 0.f, nk = 0.f;
#pragma unroll
                for (int m = 0; m < 64; m += 2) {
                    float2 kv2 = *(const float2*)&p[m];
                    float2 mv2 = *(const float2*)&mrow[m];
                    float kx = kv2.x + 1e-16f, ky = kv2.y + 1e-16f;
                    float mx = mv2.x + 1e-16f, my = mv2.y + 1e-16f;
                    dot += mx * kx + my * ky;
                    nm  += mx * mx + my * my;
                    nk  += kx * kx + ky * ky;
                }
                float sim = dot / fmaxf(sqrtf(nm) * sqrtf(nk), 1e-8f);
                float z = beta * sim;
                float r = z;
#pragma unroll
                for (int d = 32; d > 0; d >>= 1) r = fmaxf(r, __shfl_xor(r, d));
                if (lane == 0) red_s[wid] = r;
                __syncthreads();
                float zmax = fmaxf(red_s[grp * 2], red_s[grp * 2 + 1]);
                float ez = expf(z - zmax);
                r = ez;
#pragma unroll
                for (int d = 32; d > 0; d >>= 1) r += __shfl_xor(r, d);
                if (lane == 0) red_s[8 + wid] = r;
                __syncthreads();
                float zsum = red_s[8 + grp * 2] + red_s[8 + grp * 2 + 1];
                float wc = ez / zsum;
                float wgv = g * wc + (1.f - g) * wprev[lx];
                wg2_s[typ * 128 + lx] = wgv;
                __syncthreads();
                float wwv = s0 * wg2_s[typ * 128 + ((lx + 127) & 127)] + s1 * wgv
                          + s2 * wg2_s[typ * 128 + ((lx + 1) & 127)];
                float wp = powf(wwv, gamma);
                r = wp;
#pragma unroll
                for (int d = 32; d > 0; d >>= 1) r += __shfl_xor(r, d);
                if (lane == 0) red_s[wid] = r;
                __syncthreads();
                float psum = red_s[grp * 2] + red_s[grp * 2 + 1];
                float wfin = wp / (psum + 1e-16f);
                wf_s[typ * 128 + lx] = wfin;
                wprev[lx] = wfin;
                __syncthreads();
                // read vector partials (mem before this head's write)
                {
                    int m = tx & 63, p8 = tx >> 6;
                    float rv = 0.f;
                    int nb = p8 * 16;
#pragma unroll
                    for (int n8 = 0; n8 < 16; ++n8) {
                        int n = nb + n8;
                        rv += wf_s[n] * mem_s[n * 66 + m];
                    }
                    rvp_s[p8 * 66 + m] = rv;
                }
                if (tx < 64)       ea_s[tx] = sigm(proj_s[hi * 268 + 140 + tx]);
                else if (tx < 128) ea_s[tx] = proj_s[hi * 268 + 204 + (tx - 64)];
                __syncthreads();
                if (tx < 64) {
                    float rvf = 0.f;
#pragma unroll
                    for (int q = 0; q < 8; ++q) rvf += rvp_s[q * 66 + tx];
                    x_full[b * 896 + 256 + hi * 64 + tx] = rvf;
                    out[((size_t)t * 128 + b) * 640 + 512 + hi * 64 + tx] = rvf;
                }
                // erase/add (LDS only; mem never goes back to global)
#pragma unroll
                for (int e = 0; e < 8; ++e) {
                    int f = e * 512 + tx;
                    int n = f >> 5, m2 = (f & 31) * 2;
                    float w2 = wf_s[128 + n];
                    float2 mv = *(const float2*)&mem_s[n * 66 + m2];
                    mv.x = mv.x * (1.f - w2 * ea_s[m2])     + w2 * ea_s[64 + m2];
                    mv.y = mv.y * (1.f - w2 * ea_s[m2 + 1]) + w2 * ea_s[65 + m2];
                    *(float2*)&mem_s[n * 66 + m2] = mv;
                }
                __syncthreads();
            }
        }
        grid.sync();
    }
}

// ---------------- host ----------------
extern "C" void kernel_launch(void* const* d_in, const int* in_sizes, int n_in,
                              void* d_out, int out_size, void* d_ws, size_t ws_size,
                              hipStream_t stream)
{
    (void)in_sizes; (void)n_in; (void)out_size; (void)ws_size;
    const float* embs     = (const float*)d_in[0];
    const int*   lens     = (const int*)  d_in[1];
    const float* mem_bias = (const float*)d_in[2];
    const float* W_ih     = (const float*)d_in[3];
    const float* W_hh     = (const float*)d_in[4];
    const float* b_ih     = (const float*)d_in[5];
    const float* b_hh     = (const float*)d_in[6];
    const float* Wr       = (const float*)d_in[7];
    const float* br       = (const float*)d_in[8];
    const float* Ww       = (const float*)d_in[9];
    const float* bw       = (const float*)d_in[10];
    const float* h0       = (const float*)d_in[11];
    const float* c0       = (const float*)d_in[12];
    const float* r0       = (const float*)d_in[13];
    float* out = (float*)d_out;
    float* ws  = (float*)d_ws;

    hipFuncSetAttribute(reinterpret_cast<const void*>(&k_persist),
                        hipFuncAttributeMaxDynamicSharedMemorySize, SMEM_BYTES);

    void* args[] = {
        (void*)&embs, (void*)&lens, (void*)&mem_bias,
        (void*)&W_ih, (void*)&W_hh, (void*)&b_ih, (void*)&b_hh,
        (void*)&Wr, (void*)&br, (void*)&Ww, (void*)&bw,
        (void*)&h0, (void*)&c0, (void*)&r0,
        (void*)&out, (void*)&ws
    };
    hipLaunchCooperativeKernel(reinterpret_cast<void*>(&k_persist),
                               dim3(256), dim3(512), args, SMEM_BYTES, stream);
}

// Round 4
// 3084.360 us; speedup vs baseline: 4.0614x; 4.0614x over previous
//
#include <hip/hip_runtime.h>
#include <cmath>

// IDIM=256, CDIM=512, NH=2, N=128, M=64, T=64, BSZ=128
// x(t) = [emb(256) | reads0(64) | reads1(64) | h(512)], K=896, gate rows 2048.
// GEMV-style: lane = batch, weights broadcast from LDS (uniform addr).
//
// k-major x buffers (float4-packed over k):
//   embsT  [64 t][64 k4][128 b][4]    (k 0..255, precomputed once)
//   stateT [160 ks][128 b][4]         ks 0..31 = reads (k 256..383),
//                                     ks 32..159 = h (k 384..895)
//
// ---- ws float offsets ----
#define WS_EMBT  0                       // 2,097,152
#define WS_STATE 2097152                 //    81,920
#define WS_C     2179072                 //    65,536  c[ch][b]
#define WS_MEM   2244608                 // 1,048,576  mem[b][128][64]
#define WS_RW    3293184                 //    32,768  [hi][b][128]
#define WS_WWS   3325952                 //    32,768
#define WS_PART  3358720                 // 2,097,152  partials [8][2048][128]
                                         //            part2 [8][128][544] aliases
// total 5,455,872 floats (~21.9 MB)

__device__ __forceinline__ float sigm(float x) { return 1.0f / (1.0f + expf(-x)); }
__device__ __forceinline__ float softplusf(float x) {
    return fmaxf(x, 0.0f) + log1pf(expf(-fabsf(x)));
}

// ---------------- one-time: transpose embs to k-major f4-packed ----------------
__global__ __launch_bounds__(256) void k_embT(const float* __restrict__ embs,
                                              float* __restrict__ ws)
{
    int f4 = blockIdx.x * 256 + threadIdx.x;        // 524288 float4s
    int k4 = f4 & 63, b = (f4 >> 6) & 127, t = f4 >> 13;
    float4 v = *(const float4*)&embs[(size_t)(t * 128 + b) * 256 + k4 * 4];
    *(float4*)&ws[WS_EMBT + ((size_t)(t * 64 + k4) * 128 + b) * 4] = v;
}

// ---------------- one-time: init state ----------------
__global__ __launch_bounds__(256) void k_init(float* __restrict__ ws,
                                              const float* __restrict__ mem_bias,
                                              const float* __restrict__ h0,
                                              const float* __restrict__ c0,
                                              const float* __restrict__ r0)
{
    int i = blockIdx.x * 256 + threadIdx.x;          // 1,261,568 total
    if (i < 81920) {                                  // stateT
        int ks = i >> 9, rem = i & 511, c4 = rem & 3;
        int k = ks * 4 + c4;
        ws[WS_STATE + i] = (ks < 32) ? r0[k] : h0[k - 128];
        return;
    }
    int j = i - 81920;
    if (j < 65536) { ws[WS_C + j] = c0[j >> 7]; return; }          // c[ch][b]
    j -= 65536;
    if (j < 1048576) { ws[WS_MEM + j] = mem_bias[j & 8191]; return; }
    j -= 1048576;
    ws[WS_RW + j] = 0.0f;                                          // rw + wws
}

// ---------------- gates GEMV-GEMM ----------------
// grid 512 = 64 row-tiles(32) x 8 k-chunks(112); 256 thr.
// wave w: rowgrp = w>>1 (16 rows), half = w&1 (batches half*64+lane).
__global__ __launch_bounds__(256) void k_gates(
    const float* __restrict__ W_ih,   // (2048,384)
    const float* __restrict__ W_hh,   // (2048,512)
    const float* __restrict__ ws_c,
    float* __restrict__ partials,
    int t)
{
    const int tx = threadIdx.x;
    const int rt = blockIdx.x >> 3, kz = blockIdx.x & 7;
    const int r0 = rt * 32, k0 = kz * 112;

    __shared__ float w_s[32 * 112];
    const float4* w_s4 = (const float4*)w_s;

#pragma unroll
    for (int it = 0; it < 14; ++it) {
        int f = it * 256 + tx;                    // 3584 = 32 x 112
        int rl = f / 112, kk = f - rl * 112;
        int r = r0 + rl, kg = k0 + kk;
        w_s[f] = (kg < 384) ? W_ih[r * 384 + kg] : W_hh[r * 512 + (kg - 384)];
    }
    __syncthreads();

    const int lane = tx & 63, half = (tx >> 6) & 1, rowgrp = tx >> 7;
    const int b = half * 64 + lane;
    const float* embsT  = ws_c + WS_EMBT + (size_t)t * 32768;
    const float* stateT = ws_c + WS_STATE;

    float acc[16];
#pragma unroll
    for (int r = 0; r < 16; ++r) acc[r] = 0.f;

    auto ldx = [&](int k4) -> float4 {
        int k4g = kz * 28 + k4;
        const float* src = (k4g < 64) ? (embsT + (size_t)k4g * 512)
                                      : (stateT + (size_t)(k4g - 64) * 512);
        return *(const float4*)&src[b * 4];
    };

    float4 xv = ldx(0);
#pragma unroll 4
    for (int k4 = 0; k4 < 28; ++k4) {
        float4 nxt = (k4 < 27) ? ldx(k4 + 1) : xv;
#pragma unroll
        for (int r = 0; r < 16; ++r) {
            float4 wv = w_s4[(rowgrp * 16 + r) * 28 + k4];
            acc[r] += wv.x * xv.x + wv.y * xv.y + wv.z * xv.z + wv.w * xv.w;
        }
        xv = nxt;
    }
#pragma unroll
    for (int r = 0; r < 16; ++r)
        partials[(size_t)kz * 262144 + (r0 + rowgrp * 16 + r) * 128 + b] = acc[r];
}

// ---------------- LSTM pointwise ----------------
// grid 256 = 128 ch-tiles(4) x 2 batch-halves; wave w -> ch = cht*4 + w.
__global__ __launch_bounds__(256) void k_lstm(
    const float* __restrict__ partials,
    const float* __restrict__ b_ih,
    const float* __restrict__ b_hh,
    float* __restrict__ ws,
    float* __restrict__ d_out,
    const int* __restrict__ lens,
    int t)
{
    const int tx = threadIdx.x;
    const int half = blockIdx.x & 1, cht = blockIdx.x >> 1;
    const int ch = cht * 4 + (tx >> 6);
    const int lane = tx & 63, b = half * 64 + lane;

    float g4[4];
#pragma unroll
    for (int g = 0; g < 4; ++g) {
        int r = g * 512 + ch;
        float s = b_ih[r] + b_hh[r];
#pragma unroll
        for (int kzq = 0; kzq < 8; ++kzq)
            s += partials[(size_t)kzq * 262144 + r * 128 + b];
        g4[g] = s;
    }
    float* cp = ws + WS_C + ch * 128;
    float c_old = cp[b];
    float c_new = sigm(g4[1]) * c_old + sigm(g4[0]) * tanhf(g4[2]);
    float h_new = sigm(g4[3]) * tanhf(c_new);
    cp[b] = c_new;
    ws[WS_STATE + (32 + (ch >> 2)) * 512 + b * 4 + (ch & 3)] = h_new;
    d_out[((size_t)t * 128 + b) * 640 + ch] = h_new;
    if (lens[b] - 1 == t) {
        d_out[5242880 + b * 512 + ch] = h_new;
        d_out[5308416 + b * 512 + ch] = c_new;
    }
}

// ---------------- head projections GEMV-GEMM ----------------
// grid 272 = 34 j-tiles(16) x 8 k-chunks(64); 256 thr.
// wave w: rowgrp = w>>1 (8 rows), half = w&1. part2 [kz][b][544].
__global__ __launch_bounds__(256) void k_proj(
    const float* __restrict__ ws_c,
    const float* __restrict__ Wr,     // (2,70,512)
    const float* __restrict__ Ww,     // (2,198,512)
    float* __restrict__ part2)
{
    const int tx = threadIdx.x;
    const int jt = blockIdx.x >> 3, kz = blockIdx.x & 7;
    const int j0 = jt * 16, k0 = kz * 64;

    __shared__ float w_s[16 * 64];
    const float4* w_s4 = (const float4*)w_s;

#pragma unroll
    for (int it = 0; it < 4; ++it) {
        int f = it * 256 + tx;                    // 1024 = 16 x 64
        int rl = f >> 6, kk = f & 63;
        int j = j0 + rl;
        float v = 0.f;
        if (j < 536) {
            int hi = j >= 268, q = j - hi * 268;
            v = (q < 70) ? Wr[(hi * 70 + q) * 512 + k0 + kk]
                         : Ww[(hi * 198 + (q - 70)) * 512 + k0 + kk];
        }
        w_s[f] = v;
    }
    __syncthreads();

    const int lane = tx & 63, half = (tx >> 6) & 1, rowgrp = tx >> 7;
    const int b = half * 64 + lane;
    const float* stateT = ws_c + WS_STATE;

    float acc[8];
#pragma unroll
    for (int r = 0; r < 8; ++r) acc[r] = 0.f;

    float4 xv = *(const float4*)&stateT[(32 + kz * 16) * 512 + b * 4];
#pragma unroll 4
    for (int k4 = 0; k4 < 16; ++k4) {
        float4 nxt = (k4 < 15)
            ? *(const float4*)&stateT[(32 + kz * 16 + k4 + 1) * 512 + b * 4] : xv;
#pragma unroll
        for (int r = 0; r < 8; ++r) {
            float4 wv = w_s4[(rowgrp * 8 + r) * 16 + k4];
            acc[r] += wv.x * xv.x + wv.y * xv.y + wv.z * xv.z + wv.w * xv.w;
        }
        xv = nxt;
    }
#pragma unroll
    for (int r = 0; r < 8; ++r) {
        int j = j0 + rowgrp * 8 + r;
        if (j < 536) part2[(size_t)kz * 69632 + b * 544 + j] = acc[r];
    }
}

// ---------------- per-batch NTM memory ops ----------------
__global__ __launch_bounds__(256) void k_memops(
    const float* __restrict__ part2,  // [8][128][544]
    const float* __restrict__ br,     // (2,70)
    const float* __restrict__ bw,     // (2,198)
    float* __restrict__ ws,
    float* __restrict__ d_out,
    int t)
{
    const int b = blockIdx.x;
    const int tx = threadIdx.x;
    const int lx = tx & 127;
    const int grp = tx >> 7;          // 0 = read head, 1 = write head
    const int wid = tx >> 6;

    __shared__ float mem_s[128 * 66];
    __shared__ float proj_s[544];
    __shared__ float wg2_s[2 * 128];
    __shared__ float wf_s[2 * 128];
    __shared__ float red_s[16];
    __shared__ float ea_s[128];
    __shared__ float rvp_s[4 * 66];

    float* memg   = ws + WS_MEM;
    float* stateT = ws + WS_STATE;
    float* rwg    = ws + WS_RW;
    float* wwsg   = ws + WS_WWS;

    for (int j = tx; j < 536; j += 256) {
        int hi = j >= 268, q = j - hi * 268;
        float s = (q < 70) ? br[hi * 70 + q] : bw[hi * 198 + (q - 70)];
#pragma unroll
        for (int kzq = 0; kzq < 8; ++kzq)
            s += part2[(size_t)kzq * 69632 + b * 544 + j];
        proj_s[j] = s;
    }
#pragma unroll
    for (int e = 0; e < 8; ++e) {
        int f4 = e * 256 + tx;
        int n = f4 >> 4, m4 = (f4 & 15) * 4;
        float4 v = *(const float4*)&memg[b * 8192 + f4 * 4];
        *(float2*)&mem_s[n * 66 + m4]     = make_float2(v.x, v.y);
        *(float2*)&mem_s[n * 66 + m4 + 2] = make_float2(v.z, v.w);
    }
    __syncthreads();

    for (int hi = 0; hi < 2; ++hi) {
        const float* p = proj_s + hi * 268 + grp * 70;
        float* wprev_g = (grp == 0 ? rwg : wwsg) + (hi * 128 + b) * 128;

        float beta = softplusf(p[64]);
        float g = sigm(p[65]);
        float s0 = p[66], s1 = p[67], s2 = p[68];
        float sm = fmaxf(s0, fmaxf(s1, s2));
        float e0 = expf(s0 - sm), e1 = expf(s1 - sm), e2 = expf(s2 - sm);
        float sden = e0 + e1 + e2;
        s0 = e0 / sden; s1 = e1 / sden; s2 = e2 / sden;
        float gamma = 1.0f + softplusf(p[69]);

        const float* mrow = mem_s + lx * 66;
        float dot = 0.f, nm = 0.f, nk = 0.f;
#pragma unroll
        for (int m = 0; m < 64; m += 2) {
            float2 kv2 = *(const float2*)&p[m];
            float2 mv2 = *(const float2*)&mrow[m];
            float kx = kv2.x + 1e-16f, ky = kv2.y + 1e-16f;
            float mx = mv2.x + 1e-16f, my = mv2.y + 1e-16f;
            dot += mx * kx + my * ky;
            nm  += mx * mx + my * my;
            nk  += kx * kx + ky * ky;
        }
        float sim = dot / fmaxf(sqrtf(nm) * sqrtf(nk), 1e-8f);
        float z = beta * sim;

        float r = z;
#pragma unroll
        for (int d = 32; d > 0; d >>= 1) r = fmaxf(r, __shfl_xor(r, d));
        if ((tx & 63) == 0) red_s[wid] = r;
        __syncthreads();
        float zmax = fmaxf(red_s[grp * 2], red_s[grp * 2 + 1]);
        float ez = expf(z - zmax);
        r = ez;
#pragma unroll
        for (int d = 32; d > 0; d >>= 1) r += __shfl_xor(r, d);
        if ((tx & 63) == 0) red_s[8 + wid] = r;
        __syncthreads();
        float zsum = red_s[8 + grp * 2] + red_s[8 + grp * 2 + 1];
        float wc = ez / zsum;
        float wgv = g * wc + (1.f - g) * wprev_g[lx];
        wg2_s[grp * 128 + lx] = wgv;
        __syncthreads();
        float wwv = s0 * wg2_s[grp * 128 + ((lx + 127) & 127)] + s1 * wgv
                  + s2 * wg2_s[grp * 128 + ((lx + 1) & 127)];
        float wp = powf(wwv, gamma);
        r = wp;
#pragma unroll
        for (int d = 32; d > 0; d >>= 1) r += __shfl_xor(r, d);
        if ((tx & 63) == 0) red_s[wid] = r;
        __syncthreads();
        float psum = red_s[grp * 2] + red_s[grp * 2 + 1];
        float wfin = wp / (psum + 1e-16f);
        wf_s[grp * 128 + lx] = wfin;
        wprev_g[lx] = wfin;
        __syncthreads();

        {
            int m = tx & 63, p4 = tx >> 6;
            float rv = 0.f;
            const int nb = p4 * 32;
#pragma unroll
            for (int n8 = 0; n8 < 32; ++n8) {
                int n = nb + n8;
                rv += wf_s[n] * mem_s[n * 66 + m];
            }
            rvp_s[p4 * 66 + m] = rv;
        }
        if (tx < 64)        ea_s[tx] = sigm(proj_s[hi * 268 + 140 + tx]);
        else if (tx < 128)  ea_s[tx] = proj_s[hi * 268 + 204 + (tx - 64)];
        __syncthreads();

        if (tx < 64) {
            float rvf = rvp_s[tx] + rvp_s[66 + tx] + rvp_s[132 + tx] + rvp_s[198 + tx];
            stateT[((hi * 64 + tx) >> 2) * 512 + b * 4 + (tx & 3)] = rvf;
            d_out[((size_t)t * 128 + b) * 640 + 512 + hi * 64 + tx] = rvf;
        }
#pragma unroll
        for (int e = 0; e < 16; ++e) {
            int f = e * 256 + tx;
            int n = f >> 5, m2 = (f & 31) * 2;
            float w2 = wf_s[128 + n];
            float2 mv = *(const float2*)&mem_s[n * 66 + m2];
            mv.x = mv.x * (1.f - w2 * ea_s[m2])     + w2 * ea_s[64 + m2];
            mv.y = mv.y * (1.f - w2 * ea_s[m2 + 1]) + w2 * ea_s[65 + m2];
            *(float2*)&mem_s[n * 66 + m2] = mv;
            if (hi == 1) *(float2*)&memg[b * 8192 + f * 2] = mv;
        }
        __syncthreads();
    }
}

// ---------------- host ----------------
extern "C" void kernel_launch(void* const* d_in, const int* in_sizes, int n_in,
                              void* d_out, int out_size, void* d_ws, size_t ws_size,
                              hipStream_t stream)
{
    (void)in_sizes; (void)n_in; (void)out_size; (void)ws_size;
    const float* embs     = (const float*)d_in[0];
    const int*   lens     = (const int*)  d_in[1];
    const float* mem_bias = (const float*)d_in[2];
    const float* W_ih     = (const float*)d_in[3];
    const float* W_hh     = (const float*)d_in[4];
    const float* b_ih     = (const float*)d_in[5];
    const float* b_hh     = (const float*)d_in[6];
    const float* Wr       = (const float*)d_in[7];
    const float* br       = (const float*)d_in[8];
    const float* Ww       = (const float*)d_in[9];
    const float* bw       = (const float*)d_in[10];
    const float* h0       = (const float*)d_in[11];
    const float* c0       = (const float*)d_in[12];
    const float* r0       = (const float*)d_in[13];
    float* out = (float*)d_out;
    float* ws  = (float*)d_ws;
    float* partials = ws + WS_PART;
    float* part2    = ws + WS_PART;

    k_embT<<<2048, 256, 0, stream>>>(embs, ws);
    k_init<<<4928, 256, 0, stream>>>(ws, mem_bias, h0, c0, r0);
    for (int t = 0; t < 64; ++t) {
        k_gates<<<512, 256, 0, stream>>>(W_ih, W_hh, ws, partials, t);
        k_lstm<<<256, 256, 0, stream>>>(partials, b_ih, b_hh, ws, out, lens, t);
        k_proj<<<272, 256, 0, stream>>>(ws, Wr, Ww, part2);
        k_memops<<<128, 256, 0, stream>>>(part2, br, bw, ws, out, t);
    }
}

// Round 5
// 2852.013 us; speedup vs baseline: 4.3922x; 1.0815x over previous
//
#include <hip/hip_runtime.h>
#include <cmath>

// IDIM=256, CDIM=512, NH=2, N=128, M=64, T=64, BSZ=128
// x(t) = [emb(256) | reads0(64) | reads1(64) | h(512)], K=896, gate rows 2048.
// GEMV-style: lane = batch (2 per lane), weights broadcast from LDS.
//
// k-major x buffers (float4-packed over k):
//   embsT  [64 t][64 k4][128 b][4]
//   stateT [160 ks][128 b][4]   ks 0..31 = reads (k 256..383), 32..159 = h
//
// ---- ws float offsets ----
#define WS_EMBT  0                       // 2,097,152
#define WS_STATE 2097152                 //    81,920
#define WS_C     2179072                 //    65,536  c[ch][b]
#define WS_MEM   2244608                 // 1,048,576  mem[b][128][64]
#define WS_RW    3293184                 //    32,768  [hi][b][128]
#define WS_WWS   3325952                 //    32,768
#define WS_PART  3358720                 // 2,097,152  partials [8][2048][128]
                                         //            part2 [8][128][544] aliases
// total 5,455,872 floats (~21.9 MB)

#define GATES_LDS_BYTES ((3584 + 14336) * 4)   // W 14KB + x 57.3KB = 71.7KB

__device__ __forceinline__ float sigm(float x) { return 1.0f / (1.0f + expf(-x)); }
__device__ __forceinline__ float softplusf(float x) {
    return fmaxf(x, 0.0f) + log1pf(expf(-fabsf(x)));
}

// ---------------- one-time: transpose embs to k-major f4-packed ----------------
__global__ __launch_bounds__(256) void k_embT(const float* __restrict__ embs,
                                              float* __restrict__ ws)
{
    int f4 = blockIdx.x * 256 + threadIdx.x;        // 524288 float4s
    int k4 = f4 & 63, b = (f4 >> 6) & 127, t = f4 >> 13;
    float4 v = *(const float4*)&embs[(size_t)(t * 128 + b) * 256 + k4 * 4];
    *(float4*)&ws[WS_EMBT + ((size_t)(t * 64 + k4) * 128 + b) * 4] = v;
}

// ---------------- one-time: init state ----------------
__global__ __launch_bounds__(256) void k_init(float* __restrict__ ws,
                                              const float* __restrict__ mem_bias,
                                              const float* __restrict__ h0,
                                              const float* __restrict__ c0,
                                              const float* __restrict__ r0)
{
    int i = blockIdx.x * 256 + threadIdx.x;          // 1,261,568 total
    if (i < 81920) {                                  // stateT
        int ks = i >> 9, rem = i & 511, c4 = rem & 3;
        int k = ks * 4 + c4;
        ws[WS_STATE + i] = (ks < 32) ? r0[k] : h0[k - 128];
        return;
    }
    int j = i - 81920;
    if (j < 65536) { ws[WS_C + j] = c0[j >> 7]; return; }          // c[ch][b]
    j -= 65536;
    if (j < 1048576) { ws[WS_MEM + j] = mem_bias[j & 8191]; return; }
    j -= 1048576;
    ws[WS_RW + j] = 0.0f;                                          // rw + wws
}

// ---------------- gates GEMV-GEMM ----------------
// grid 512 = 64 row-tiles(32) x 8 k-chunks(112); 256 thr; 2 blocks/CU.
// wave wid: rows wid*8..wid*8+7; each lane handles batches (lane, lane+64).
// W and the x-slice are bulk-staged to LDS; inner loop is pure LDS + FMA.
__global__ void __launch_bounds__(256, 2) k_gates(
    const float* __restrict__ W_ih,   // (2048,384)
    const float* __restrict__ W_hh,   // (2048,512)
    const float* __restrict__ ws_c,
    float* __restrict__ partials,
    int t)
{
    extern __shared__ float sm[];
    float4* w_s4 = (float4*)sm;              // [32 rows][28 kq]
    float4* x_s4 = (float4*)(sm + 3584);     // [28 k4][128 b]

    const int tx = threadIdx.x;
    const int rt = blockIdx.x >> 3, kz = blockIdx.x & 7;
    const int r0g = rt * 32, k0 = kz * 112;

    // stage W: 896 f4 (rows 32 x 28 f4)
#pragma unroll
    for (int it = 0; it < 4; ++it) {
        int f = it * 256 + tx;
        if (f < 896) {
            int rl = f / 28, kq = f - rl * 28;
            int kg = k0 + kq * 4, r = r0g + rl;
            float4 v = (kg < 384) ? *(const float4*)&W_ih[r * 384 + kg]
                                  : *(const float4*)&W_hh[r * 512 + (kg - 384)];
            w_s4[f] = v;
        }
    }
    // stage x: 3584 f4 ([28 k4][128 b])
    const float* embsT  = ws_c + WS_EMBT + (size_t)t * 32768;
    const float* stateT = ws_c + WS_STATE;
#pragma unroll
    for (int it = 0; it < 14; ++it) {
        int f = it * 256 + tx;
        int k4 = f >> 7, b = f & 127;
        int k4g = kz * 28 + k4;
        const float* src = (k4g < 64) ? &embsT[(size_t)k4g * 512 + b * 4]
                                      : &stateT[(size_t)(k4g - 64) * 512 + b * 4];
        x_s4[f] = *(const float4*)src;
    }
    __syncthreads();

    const int lane = tx & 63, wid = tx >> 6;
    const int wr0 = wid * 8;
    float acc0[8] = {}, acc1[8] = {};
#pragma unroll 4
    for (int k4 = 0; k4 < 28; ++k4) {
        float4 xv0 = x_s4[k4 * 128 + lane];
        float4 xv1 = x_s4[k4 * 128 + 64 + lane];
#pragma unroll
        for (int r = 0; r < 8; ++r) {
            float4 wv = w_s4[(wr0 + r) * 28 + k4];
            acc0[r] += wv.x * xv0.x + wv.y * xv0.y + wv.z * xv0.z + wv.w * xv0.w;
            acc1[r] += wv.x * xv1.x + wv.y * xv1.y + wv.z * xv1.z + wv.w * xv1.w;
        }
    }
#pragma unroll
    for (int r = 0; r < 8; ++r) {
        int row = r0g + wr0 + r;
        partials[(size_t)kz * 262144 + row * 128 + lane]      = acc0[r];
        partials[(size_t)kz * 262144 + row * 128 + 64 + lane] = acc1[r];
    }
}

// ---------------- LSTM pointwise ----------------
// grid 256 = 128 ch-tiles(4) x 2 batch-halves; wave w -> ch = cht*4 + w.
__global__ __launch_bounds__(256) void k_lstm(
    const float* __restrict__ partials,
    const float* __restrict__ b_ih,
    const float* __restrict__ b_hh,
    float* __restrict__ ws,
    float* __restrict__ d_out,
    const int* __restrict__ lens,
    int t)
{
    const int tx = threadIdx.x;
    const int half = blockIdx.x & 1, cht = blockIdx.x >> 1;
    const int ch = cht * 4 + (tx >> 6);
    const int lane = tx & 63, b = half * 64 + lane;

    float g4[4];
#pragma unroll
    for (int g = 0; g < 4; ++g) {
        int r = g * 512 + ch;
        float s = b_ih[r] + b_hh[r];
#pragma unroll
        for (int kzq = 0; kzq < 8; ++kzq)
            s += partials[(size_t)kzq * 262144 + r * 128 + b];
        g4[g] = s;
    }
    float* cp = ws + WS_C + ch * 128;
    float c_old = cp[b];
    float c_new = sigm(g4[1]) * c_old + sigm(g4[0]) * tanhf(g4[2]);
    float h_new = sigm(g4[3]) * tanhf(c_new);
    cp[b] = c_new;
    ws[WS_STATE + (32 + (ch >> 2)) * 512 + b * 4 + (ch & 3)] = h_new;
    d_out[((size_t)t * 128 + b) * 640 + ch] = h_new;
    if (lens[b] - 1 == t) {
        d_out[5242880 + b * 512 + ch] = h_new;
        d_out[5308416 + b * 512 + ch] = c_new;
    }
}

// ---------------- head projections GEMV-GEMM ----------------
// grid 272 = 34 j-tiles(16) x 8 k-chunks(64); 256 thr.
// wave wid: j rows wid*4..+3; lane batches (lane, lane+64). Bulk LDS staging.
__global__ __launch_bounds__(256) void k_proj(
    const float* __restrict__ ws_c,
    const float* __restrict__ Wr,     // (2,70,512)
    const float* __restrict__ Ww,     // (2,198,512)
    float* __restrict__ part2)        // [kz][b][544]
{
    __shared__ float w_s[16 * 64];        // 4KB
    __shared__ float x_s[16 * 128 * 4];   // 32KB
    float4* w_s4 = (float4*)w_s;
    float4* x_s4 = (float4*)x_s;

    const int tx = threadIdx.x;
    const int jt = blockIdx.x >> 3, kz = blockIdx.x & 7;
    const int j0 = jt * 16, k0 = kz * 64;
    const float* stateT = ws_c + WS_STATE;

    // stage W: 256 f4 (16 j x 16 kq)
    {
        int rl = tx >> 4, kq = tx & 15;
        int j = j0 + rl;
        float4 v = make_float4(0.f, 0.f, 0.f, 0.f);
        if (j < 536) {
            int hi = j >= 268, q = j - hi * 268;
            v = (q < 70) ? *(const float4*)&Wr[(hi * 70 + q) * 512 + k0 + kq * 4]
                         : *(const float4*)&Ww[(hi * 198 + (q - 70)) * 512 + k0 + kq * 4];
        }
        w_s4[tx] = v;
    }
    // stage x: 2048 f4 ([16 k4][128 b]) from h part of stateT
#pragma unroll
    for (int it = 0; it < 8; ++it) {
        int f = it * 256 + tx;
        int k4 = f >> 7, b = f & 127;
        x_s4[f] = *(const float4*)&stateT[(size_t)(32 + kz * 16 + k4) * 512 + b * 4];
    }
    __syncthreads();

    const int lane = tx & 63, wid = tx >> 6;
    const int jw0 = wid * 4;
    float acc0[4] = {}, acc1[4] = {};
#pragma unroll 4
    for (int k4 = 0; k4 < 16; ++k4) {
        float4 xv0 = x_s4[k4 * 128 + lane];
        float4 xv1 = x_s4[k4 * 128 + 64 + lane];
#pragma unroll
        for (int r = 0; r < 4; ++r) {
            float4 wv = w_s4[(jw0 + r) * 16 + k4];
            acc0[r] += wv.x * xv0.x + wv.y * xv0.y + wv.z * xv0.z + wv.w * xv0.w;
            acc1[r] += wv.x * xv1.x + wv.y * xv1.y + wv.z * xv1.z + wv.w * xv1.w;
        }
    }
#pragma unroll
    for (int r = 0; r < 4; ++r) {
        int j = j0 + jw0 + r;
        if (j < 536) {
            part2[(size_t)kz * 69632 + lane * 544 + j]        = acc0[r];
            part2[(size_t)kz * 69632 + (lane + 64) * 544 + j] = acc1[r];
        }
    }
}

// ---------------- per-batch NTM memory ops ----------------
__global__ __launch_bounds__(256) void k_memops(
    const float* __restrict__ part2,  // [8][128][544]
    const float* __restrict__ br,     // (2,70)
    const float* __restrict__ bw,     // (2,198)
    float* __restrict__ ws,
    float* __restrict__ d_out,
    int t)
{
    const int b = blockIdx.x;
    const int tx = threadIdx.x;
    const int lx = tx & 127;
    const int grp = tx >> 7;          // 0 = read head, 1 = write head
    const int wid = tx >> 6;

    __shared__ float mem_s[128 * 66];
    __shared__ float proj_s[544];
    __shared__ float wg2_s[2 * 128];
    __shared__ float wf_s[2 * 128];
    __shared__ float red_s[16];
    __shared__ float ea_s[128];
    __shared__ float rvp_s[4 * 66];

    float* memg   = ws + WS_MEM;
    float* stateT = ws + WS_STATE;
    float* rwg    = ws + WS_RW;
    float* wwsg   = ws + WS_WWS;

    for (int j = tx; j < 536; j += 256) {
        int hi = j >= 268, q = j - hi * 268;
        float s = (q < 70) ? br[hi * 70 + q] : bw[hi * 198 + (q - 70)];
#pragma unroll
        for (int kzq = 0; kzq < 8; ++kzq)
            s += part2[(size_t)kzq * 69632 + b * 544 + j];
        proj_s[j] = s;
    }
#pragma unroll
    for (int e = 0; e < 8; ++e) {
        int f4 = e * 256 + tx;
        int n = f4 >> 4, m4 = (f4 & 15) * 4;
        float4 v = *(const float4*)&memg[b * 8192 + f4 * 4];
        *(float2*)&mem_s[n * 66 + m4]     = make_float2(v.x, v.y);
        *(float2*)&mem_s[n * 66 + m4 + 2] = make_float2(v.z, v.w);
    }
    __syncthreads();

    for (int hi = 0; hi < 2; ++hi) {
        const float* p = proj_s + hi * 268 + grp * 70;
        float* wprev_g = (grp == 0 ? rwg : wwsg) + (hi * 128 + b) * 128;

        float beta = softplusf(p[64]);
        float g = sigm(p[65]);
        float s0 = p[66], s1 = p[67], s2 = p[68];
        float sm = fmaxf(s0, fmaxf(s1, s2));
        float e0 = expf(s0 - sm), e1 = expf(s1 - sm), e2 = expf(s2 - sm);
        float sden = e0 + e1 + e2;
        s0 = e0 / sden; s1 = e1 / sden; s2 = e2 / sden;
        float gamma = 1.0f + softplusf(p[69]);

        const float* mrow = mem_s + lx * 66;
        float dot = 0.f, nm = 0.f, nk = 0.f;
#pragma unroll
        for (int m = 0; m < 64; m += 2) {
            float2 kv2 = *(const float2*)&p[m];
            float2 mv2 = *(const float2*)&mrow[m];
            float kx = kv2.x + 1e-16f, ky = kv2.y + 1e-16f;
            float mx = mv2.x + 1e-16f, my = mv2.y + 1e-16f;
            dot += mx * kx + my * ky;
            nm  += mx * mx + my * my;
            nk  += kx * kx + ky * ky;
        }
        float sim = dot / fmaxf(sqrtf(nm) * sqrtf(nk), 1e-8f);
        float z = beta * sim;

        float r = z;
#pragma unroll
        for (int d = 32; d > 0; d >>= 1) r = fmaxf(r, __shfl_xor(r, d));
        if ((tx & 63) == 0) red_s[wid] = r;
        __syncthreads();
        float zmax = fmaxf(red_s[grp * 2], red_s[grp * 2 + 1]);
        float ez = expf(z - zmax);
        r = ez;
#pragma unroll
        for (int d = 32; d > 0; d >>= 1) r += __shfl_xor(r, d);
        if ((tx & 63) == 0) red_s[8 + wid] = r;
        __syncthreads();
        float zsum = red_s[8 + grp * 2] + red_s[8 + grp * 2 + 1];
        float wc = ez / zsum;
        float wgv = g * wc + (1.f - g) * wprev_g[lx];
        wg2_s[grp * 128 + lx] = wgv;
        __syncthreads();
        float wwv = s0 * wg2_s[grp * 128 + ((lx + 127) & 127)] + s1 * wgv
                  + s2 * wg2_s[grp * 128 + ((lx + 1) & 127)];
        float wp = powf(wwv, gamma);
        r = wp;
#pragma unroll
        for (int d = 32; d > 0; d >>= 1) r += __shfl_xor(r, d);
        if ((tx & 63) == 0) red_s[wid] = r;
        __syncthreads();
        float psum = red_s[grp * 2] + red_s[grp * 2 + 1];
        float wfin = wp / (psum + 1e-16f);
        wf_s[grp * 128 + lx] = wfin;
        wprev_g[lx] = wfin;
        __syncthreads();

        {
            int m = tx & 63, p4 = tx >> 6;
            float rv = 0.f;
            const int nb = p4 * 32;
#pragma unroll
            for (int n8 = 0; n8 < 32; ++n8) {
                int n = nb + n8;
                rv += wf_s[n] * mem_s[n * 66 + m];
            }
            rvp_s[p4 * 66 + m] = rv;
        }
        if (tx < 64)        ea_s[tx] = sigm(proj_s[hi * 268 + 140 + tx]);
        else if (tx < 128)  ea_s[tx] = proj_s[hi * 268 + 204 + (tx - 64)];
        __syncthreads();

        if (tx < 64) {
            float rvf = rvp_s[tx] + rvp_s[66 + tx] + rvp_s[132 + tx] + rvp_s[198 + tx];
            stateT[((hi * 64 + tx) >> 2) * 512 + b * 4 + (tx & 3)] = rvf;
            d_out[((size_t)t * 128 + b) * 640 + 512 + hi * 64 + tx] = rvf;
        }
#pragma unroll
        for (int e = 0; e < 16; ++e) {
            int f = e * 256 + tx;
            int n = f >> 5, m2 = (f & 31) * 2;
            float w2 = wf_s[128 + n];
            float2 mv = *(const float2*)&mem_s[n * 66 + m2];
            mv.x = mv.x * (1.f - w2 * ea_s[m2])     + w2 * ea_s[64 + m2];
            mv.y = mv.y * (1.f - w2 * ea_s[m2 + 1]) + w2 * ea_s[65 + m2];
            *(float2*)&mem_s[n * 66 + m2] = mv;
            if (hi == 1) *(float2*)&memg[b * 8192 + f * 2] = mv;
        }
        __syncthreads();
    }
}

// ---------------- host ----------------
extern "C" void kernel_launch(void* const* d_in, const int* in_sizes, int n_in,
                              void* d_out, int out_size, void* d_ws, size_t ws_size,
                              hipStream_t stream)
{
    (void)in_sizes; (void)n_in; (void)out_size; (void)ws_size;
    const float* embs     = (const float*)d_in[0];
    const int*   lens     = (const int*)  d_in[1];
    const float* mem_bias = (const float*)d_in[2];
    const float* W_ih     = (const float*)d_in[3];
    const float* W_hh     = (const float*)d_in[4];
    const float* b_ih     = (const float*)d_in[5];
    const float* b_hh     = (const float*)d_in[6];
    const float* Wr       = (const float*)d_in[7];
    const float* br       = (const float*)d_in[8];
    const float* Ww       = (const float*)d_in[9];
    const float* bw       = (const float*)d_in[10];
    const float* h0       = (const float*)d_in[11];
    const float* c0       = (const float*)d_in[12];
    const float* r0       = (const float*)d_in[13];
    float* out = (float*)d_out;
    float* ws  = (float*)d_ws;
    float* partials = ws + WS_PART;
    float* part2    = ws + WS_PART;

    hipFuncSetAttribute(reinterpret_cast<const void*>(&k_gates),
                        hipFuncAttributeMaxDynamicSharedMemorySize, GATES_LDS_BYTES);

    k_embT<<<2048, 256, 0, stream>>>(embs, ws);
    k_init<<<4928, 256, 0, stream>>>(ws, mem_bias, h0, c0, r0);
    for (int t = 0; t < 64; ++t) {
        k_gates<<<512, 256, GATES_LDS_BYTES, stream>>>(W_ih, W_hh, ws, partials, t);
        k_lstm<<<256, 256, 0, stream>>>(partials, b_ih, b_hh, ws, out, lens, t);
        k_proj<<<272, 256, 0, stream>>>(ws, Wr, Ww, part2);
        k_memops<<<128, 256, 0, stream>>>(part2, br, bw, ws, out, t);
    }
}